// Round 2
// 678.748 us; speedup vs baseline: 1.0764x; 1.0764x over previous
//
#include <hip/hip_runtime.h>
#include <math.h>

// FieldFormer fused kernel, round 5.
// vs round 3 (727us, absmax 0.0039, passing):
//  - phase 1+2 fused in registers (bit-identical fmaf/reduction order; kills the
//    33KB fp32 hf LDS round-trip and one barrier).
//  - GEMM1->GEMM2 staging k-split into a [64][136] half buffer: GEMM1 computes
//    x cols 0..127 -> stage -> GEMM2 partial (k 0..127, persistent acc2) ->
//    barrier -> GEMM1 cols 128..255 into same buffer -> GEMM2 finish.
//    Per-output accumulation order unchanged (kk 0..7 sequential) => bit-identical.
//  - LDS 52.7KB -> ~35.9KB: 3 -> 4 blocks/CU (12 -> 16 waves/CU) at QB=2
//    (round 4 showed QB=1 doubles per-query weight traffic: keep QB=2).
//  - round-4's fused pool epilogue REVERTED (suspect for the absmax/nondet
//    failure); pooling is round-3's LDS path, pool/pln alias the dead s_x half.
#define KN 32
#define DD 128
#define FF 256
#define QB 2
#define MROWS (QB * KN)      // 64
#define HP 136               // pitch (ushort) for both s_hA and s_x half, 128+8

typedef __attribute__((ext_vector_type(8))) short bf16x8;
typedef __attribute__((ext_vector_type(4))) float f32x4;

__device__ __forceinline__ unsigned short f2bf(float x) {
    union { float f; unsigned u; } c; c.f = x;
    unsigned r = c.u + 0x7fffu + ((c.u >> 16) & 1u);   // RNE
    return (unsigned short)(r >> 16);
}
__device__ __forceinline__ float bf2f(unsigned short h) {
    union { unsigned u; float f; } c; c.u = ((unsigned)h) << 16;
    return c.f;
}

// gelu(x) = 0.5*x*(1+erf(x/sqrt2)), erf via A&S 7.1.26 (|err|<=1.5e-7).
__device__ __forceinline__ float gelu_f(float x) {
    float z  = __builtin_fabsf(x) * 0.70710678118654752440f;
    float z2 = z * z;
    float e  = __builtin_amdgcn_exp2f(z2 * -1.4426950408889634f);   // exp(-z^2)
    float t  = __builtin_amdgcn_rcpf(fmaf(0.3275911f, z, 1.0f));
    float p  = fmaf(1.061405429f, t, -1.453152027f);
    p = fmaf(p, t, 1.421413741f);
    p = fmaf(p, t, -0.284496736f);
    p = fmaf(p, t, 0.254829592f);
    p = p * t;
    float erfz = fmaf(-p, e, 1.0f);                 // erf(|x|/sqrt2)
    float erfs = (x < 0.0f) ? -erfz : erfz;
    float hx = 0.5f * x;
    return fmaf(hx, erfs, hx);
}

// Prep: w1 [256,128] -> bf16, w2 [128,256] -> bf16, hw1 [256,256] -> transposed
// packed pairs hw1p[c2*256+f] = (bf16(hw1[f][2c2]), bf16(hw1[f][2c2+1])).
__global__ void prep_kernel(const float* __restrict__ w1,
                            const float* __restrict__ w2,
                            const float* __restrict__ hw1,
                            unsigned short* __restrict__ w1b,
                            unsigned short* __restrict__ w2b,
                            unsigned* __restrict__ hw1p) {
    int i = blockIdx.x * 256 + threadIdx.x;   // 0..32767
    w1b[i] = f2bf(w1[i]);
    w2b[i] = f2bf(w2[i]);
    int c2 = i >> 8, f = i & 255;
    unsigned lo = f2bf(hw1[f * 256 + 2 * c2]);
    unsigned hi = f2bf(hw1[f * 256 + 2 * c2 + 1]);
    hw1p[i] = lo | (hi << 16);
}

__launch_bounds__(256, 4)
__global__ void ff_mfma_kernel(
    const float* __restrict__ xyt_q,
    const float* __restrict__ obs_coords,
    const float* __restrict__ obs_vals,
    const int*   __restrict__ nb_idx,
    const float* __restrict__ log_gammas,
    const float* __restrict__ w_in,   // [128,4]
    const float* __restrict__ b_in,
    const float* __restrict__ ln1_g,
    const float* __restrict__ ln1_b,
    const unsigned short* __restrict__ w1b,  // [256,128] bf16
    const float* __restrict__ b1,
    const unsigned short* __restrict__ w2b,  // [128,256] bf16
    const float* __restrict__ b2,
    const float* __restrict__ hln_g,
    const float* __restrict__ hln_b,
    const unsigned* __restrict__ hw1p,       // [128,256] packed bf16 pairs
    const float* __restrict__ hb1,
    const float* __restrict__ hw2,
    const float* __restrict__ hb2,
    float* __restrict__ out)
{
    __shared__ __align__(16) unsigned short s_hA[MROWS * HP];  // 17408: h_ln, then h2
    __shared__ __align__(16) unsigned short s_x[MROWS * HP];   // 17408: x half-cols
    __shared__ __align__(16) float s_tokf[MROWS][4];           // 1024
    __shared__ float s_mu[QB], s_sig[QB];
    __shared__ float s_red[4][QB];

    const int t    = threadIdx.x;
    const int lane = t & 63;
    const int wv   = t >> 6;
    const int m16  = lane & 15;
    const int quad = lane >> 4;
    const int q0   = blockIdx.x * QB;

    float* s_pool = (float*)s_x;         // [2][256] after GEMM2 (s_x dead)
    float* s_pln  = s_pool + 512;        // [2][256] after head LN

    // ---- Phase 0: gather neighbors, tokens, mu/sigma (ddof=1, clip 1e-3) ----
    if (t < MROWS) {
        int qi = t >> 5, j = t & 31;
        int q = q0 + qi;
        int idx = nb_idx[q * KN + j];
        float v = obs_vals[idx];
        float g0 = expf(log_gammas[0]), g1 = expf(log_gammas[1]), g2 = expf(log_gammas[2]);
        s_tokf[t][0] = (obs_coords[idx * 3 + 0] - xyt_q[q * 3 + 0]) * g0;
        s_tokf[t][1] = (obs_coords[idx * 3 + 1] - xyt_q[q * 3 + 1]) * g1;
        s_tokf[t][2] = (obs_coords[idx * 3 + 2] - xyt_q[q * 3 + 2]) * g2;
        float s = v, ss = v * v;
        #pragma unroll
        for (int m = 1; m < 32; m <<= 1) {
            s  += __shfl_xor(s, m);
            ss += __shfl_xor(ss, m);
        }
        float mu  = s * (1.0f / KN);
        float var = (ss - (float)KN * mu * mu) * (1.0f / (KN - 1));
        float sig = fmaxf(sqrtf(fmaxf(var, 0.0f)), 1e-3f);
        if (j == 0) { s_mu[qi] = mu; s_sig[qi] = sig; }
        s_tokf[t][3] = (v - mu) / sig;
    }
    __syncthreads();

    // ---- Phase 1+2 fused: h = gelu(tok @ w_in^T + b_in), LN over 128 -> bf16 s_hA.
    // Wave wv owns tokens [wv*16, wv*16+16); lane owns d=lane and d=lane+64.
    // Same fmaf chain + 64-lane reduction order as round 3 => bit-identical.
    {
        float4 wlo = ((const float4*)w_in)[lane];
        float4 whi = ((const float4*)w_in)[lane + 64];
        float blo = b_in[lane],  bhi = b_in[lane + 64];
        float glo = ln1_g[lane], ghi = ln1_g[lane + 64];
        float clo = ln1_b[lane], chi = ln1_b[lane + 64];
        #pragma unroll
        for (int i = 0; i < 16; i++) {
            int tok = wv * 16 + i;
            float4 tk = *(const float4*)&s_tokf[tok][0];
            float a0 = fmaf(wlo.x, tk.x, fmaf(wlo.y, tk.y, fmaf(wlo.z, tk.z, fmaf(wlo.w, tk.w, blo))));
            float a1 = fmaf(whi.x, tk.x, fmaf(whi.y, tk.y, fmaf(whi.z, tk.z, fmaf(whi.w, tk.w, bhi))));
            float v0 = gelu_f(a0), v1 = gelu_f(a1);
            float s = v0 + v1, ss = v0 * v0 + v1 * v1;
            #pragma unroll
            for (int m = 1; m < 64; m <<= 1) {
                s  += __shfl_xor(s, m);
                ss += __shfl_xor(ss, m);
            }
            float mean = s * (1.0f / DD);
            float var  = ss * (1.0f / DD) - mean * mean;
            float rstd = rsqrtf(fmaxf(var, 0.0f) + 1e-5f);
            s_hA[tok * HP + lane]      = f2bf((v0 - mean) * rstd * glo + clo);
            s_hA[tok * HP + 64 + lane] = f2bf((v1 - mean) * rstd * ghi + chi);
        }
    }
    __syncthreads();

    // ---- Phases 3+4 k-split: per half h, GEMM1 (x cols h*128..h*128+127) into
    //      s_x, then GEMM2 partial k-accumulate into persistent acc2.
    f32x4 acc2[4][2];
    #pragma unroll
    for (int rt = 0; rt < 4; rt++)
        #pragma unroll
        for (int ct = 0; ct < 2; ct++)
            acc2[rt][ct] = (f32x4){0.f, 0.f, 0.f, 0.f};

    #pragma unroll
    for (int h = 0; h < 2; h++) {
        // GEMM1 half: x[:, h*128 + wv*32 + ct*16 + m16] = gelu(hln @ w1^T + b1)
        {
            bf16x8 B[2][4];
            #pragma unroll
            for (int ct = 0; ct < 2; ct++)
                #pragma unroll
                for (int kk = 0; kk < 4; kk++)
                    B[ct][kk] = *(const bf16x8*)&w1b[(h * 128 + wv * 32 + ct * 16 + m16) * 128 + kk * 32 + quad * 8];
            #pragma unroll
            for (int rt = 0; rt < 4; rt++) {
                bf16x8 A[4];
                #pragma unroll
                for (int kk = 0; kk < 4; kk++)
                    A[kk] = *(const bf16x8*)&s_hA[(rt * 16 + m16) * HP + kk * 32 + quad * 8];
                #pragma unroll
                for (int ct = 0; ct < 2; ct++) {
                    f32x4 acc = {0.f, 0.f, 0.f, 0.f};
                    #pragma unroll
                    for (int kk = 0; kk < 4; kk++)
                        acc = __builtin_amdgcn_mfma_f32_16x16x32_bf16(A[kk], B[ct][kk], acc, 0, 0, 0);
                    int cl = wv * 32 + ct * 16 + m16;          // local col 0..127
                    float bb = b1[h * 128 + cl];
                    #pragma unroll
                    for (int r = 0; r < 4; r++)
                        s_x[(rt * 16 + quad * 4 + r) * HP + cl] = f2bf(gelu_f(acc[r] + bb));
                }
            }
        }
        __syncthreads();
        // GEMM2 partial: acc2 += x_half @ w2[:, h*128 .. h*128+127]^T
        {
            bf16x8 B2[2][4];
            #pragma unroll
            for (int ct = 0; ct < 2; ct++)
                #pragma unroll
                for (int kk = 0; kk < 4; kk++)
                    B2[ct][kk] = *(const bf16x8*)&w2b[(wv * 32 + ct * 16 + m16) * 256 + h * 128 + kk * 32 + quad * 8];
            #pragma unroll
            for (int rt = 0; rt < 4; rt++) {
                bf16x8 A[4];
                #pragma unroll
                for (int kk = 0; kk < 4; kk++)
                    A[kk] = *(const bf16x8*)&s_x[(rt * 16 + m16) * HP + kk * 32 + quad * 8];
                #pragma unroll
                for (int ct = 0; ct < 2; ct++)
                    #pragma unroll
                    for (int kk = 0; kk < 4; kk++)
                        acc2[rt][ct] = __builtin_amdgcn_mfma_f32_16x16x32_bf16(A[kk], B2[ct][kk], acc2[rt][ct], 0, 0, 0);
            }
        }
        __syncthreads();   // h=0: before s_x overwrite; h=1: before h2/pool writes
    }

    // ---- GEMM2 epilogue: h2 = gelu(acc2 + b2) -> bf16 s_hA (s_hA reads done) ----
    #pragma unroll
    for (int rt = 0; rt < 4; rt++)
        #pragma unroll
        for (int ct = 0; ct < 2; ct++) {
            int col = wv * 32 + ct * 16 + m16;
            float bb = b2[col];
            #pragma unroll
            for (int r = 0; r < 4; r++)
                s_hA[(rt * 16 + quad * 4 + r) * HP + col] = f2bf(gelu_f(acc2[rt][ct][r] + bb));
        }
    __syncthreads();

    // ---- Phase 5: pool mean/max over K=32 per query (h2 in s_hA), round-3 path ----
    {
        int qi = t >> 7, d = t & 127;
        float sm = 0.f, mx = -INFINITY;
        #pragma unroll
        for (int k = 0; k < KN; k++) {
            float v = bf2f(s_hA[(qi * KN + k) * HP + d]);
            sm += v; mx = fmaxf(mx, v);
        }
        s_pool[qi * 256 + d]       = sm * (1.0f / KN);
        s_pool[qi * 256 + 128 + d] = mx;
    }
    __syncthreads();

    // ---- Phase 6: head LN over 256 (one wave per query) ----
    if (t < 128) {
        int qi = t >> 6, l = t & 63;
        float v0 = s_pool[qi * 256 + l],       v1 = s_pool[qi * 256 + l + 64];
        float v2 = s_pool[qi * 256 + l + 128], v3 = s_pool[qi * 256 + l + 192];
        float s = v0 + v1 + v2 + v3;
        float ss = v0 * v0 + v1 * v1 + v2 * v2 + v3 * v3;
        #pragma unroll
        for (int m = 1; m < 64; m <<= 1) {
            s  += __shfl_xor(s, m);
            ss += __shfl_xor(ss, m);
        }
        float mean = s * (1.0f / (2 * DD));
        float var  = ss * (1.0f / (2 * DD)) - mean * mean;
        float rstd = rsqrtf(fmaxf(var, 0.0f) + 1e-5f);
        s_pln[qi * 256 + l]       = (v0 - mean) * rstd * hln_g[l]       + hln_b[l];
        s_pln[qi * 256 + l + 64]  = (v1 - mean) * rstd * hln_g[l + 64]  + hln_b[l + 64];
        s_pln[qi * 256 + l + 128] = (v2 - mean) * rstd * hln_g[l + 128] + hln_b[l + 128];
        s_pln[qi * 256 + l + 192] = (v3 - mean) * rstd * hln_g[l + 192] + hln_b[l + 192];
    }
    __syncthreads();

    // ---- Phase 7: head MLP, thread t = hidden unit f, both queries ----
    {
        float a0 = hb1[t], a1 = a0;
        #pragma unroll 8
        for (int c2 = 0; c2 < 128; c2++) {
            unsigned v = hw1p[c2 * 256 + t];          // coalesced 4B/lane
            float w0 = bf2f((unsigned short)(v & 0xffffu));
            float w1 = bf2f((unsigned short)(v >> 16));
            float p00 = s_pln[2 * c2], p01 = s_pln[2 * c2 + 1];
            float p10 = s_pln[256 + 2 * c2], p11 = s_pln[256 + 2 * c2 + 1];
            a0 = fmaf(w0, p00, fmaf(w1, p01, a0));
            a1 = fmaf(w0, p10, fmaf(w1, p11, a1));
        }
        float hv = hw2[t];
        float c0 = gelu_f(a0) * hv, c1 = gelu_f(a1) * hv;
        #pragma unroll
        for (int m = 1; m < 64; m <<= 1) {
            c0 += __shfl_xor(c0, m);
            c1 += __shfl_xor(c1, m);
        }
        if (lane == 0) { s_red[wv][0] = c0; s_red[wv][1] = c1; }
    }
    __syncthreads();
    if (t == 0) {
        float u0 = s_red[0][0] + s_red[1][0] + s_red[2][0] + s_red[3][0] + hb2[0];
        float u1 = s_red[0][1] + s_red[1][1] + s_red[2][1] + s_red[3][1] + hb2[0];
        out[q0 + 0] = u0 * s_sig[0] + s_mu[0];
        out[q0 + 1] = u1 * s_sig[1] + s_mu[1];
    }
}

extern "C" void kernel_launch(void* const* d_in, const int* in_sizes, int n_in,
                              void* d_out, int out_size, void* d_ws, size_t ws_size,
                              hipStream_t stream)
{
    const float* xyt_q      = (const float*)d_in[0];
    const float* obs_coords = (const float*)d_in[1];
    const float* obs_vals   = (const float*)d_in[2];
    const int*   nb_idx     = (const int*)d_in[3];
    const float* log_gammas = (const float*)d_in[4];
    const float* w_in  = (const float*)d_in[5];
    const float* b_in  = (const float*)d_in[6];
    const float* ln1_g = (const float*)d_in[7];
    const float* ln1_b = (const float*)d_in[8];
    const float* w1    = (const float*)d_in[9];
    const float* b1    = (const float*)d_in[10];
    const float* w2    = (const float*)d_in[11];
    const float* b2    = (const float*)d_in[12];
    const float* hln_g = (const float*)d_in[13];
    const float* hln_b = (const float*)d_in[14];
    const float* hw1   = (const float*)d_in[15];
    const float* hb1   = (const float*)d_in[16];
    const float* hw2   = (const float*)d_in[17];
    const float* hb2   = (const float*)d_in[18];
    float* out = (float*)d_out;

    const int Q = in_sizes[0] / 3;   // 32768

    unsigned short* w1b  = (unsigned short*)d_ws;
    unsigned short* w2b  = w1b + 32768;
    unsigned*       hw1p = (unsigned*)((char*)d_ws + 131072);

    prep_kernel<<<128, 256, 0, stream>>>(w1, w2, hw1, w1b, w2b, hw1p);

    ff_mfma_kernel<<<Q / QB, 256, 0, stream>>>(
        xyt_q, obs_coords, obs_vals, nb_idx, log_gammas,
        w_in, b_in, ln1_g, ln1_b,
        w1b, b1, w2b, b2,
        hln_g, hln_b, hw1p, hb1, hw2, hb2, out);
}